// Round 1
// baseline (1961.848 us; speedup 1.0000x reference)
//
#include <hip/hip_runtime.h>

// Problem constants (reference: B=2, N=2048, DIM=1024, INTER=1024, HEAD=16, N_SEG=4)
#define BB 2
#define NN 2048
#define DIM 1024
#define INTER 1024
#define NHEAD 16
#define HDIM 64          // INTER / NHEAD
#define NSEG 4
#define QKVW (3 * INTER) // 3072

// ---------------------------------------------------------------------------
// Tiled fp32 GEMM: C[M,N] = A[M,K] @ B[K,N], all row-major.
// 64x64 tile per 256-thread block, BK=16, 4x4 micro-tile per thread.
// ---------------------------------------------------------------------------
#define TILE 64
#define BK 16

__global__ __launch_bounds__(256) void gemm_fp32(const float* __restrict__ A,
                                                 const float* __restrict__ B,
                                                 float* __restrict__ C,
                                                 int M, int N, int K) {
    __shared__ float As[BK][TILE + 4];   // [kk][m], +4 pad keeps 16B align, breaks conflicts
    __shared__ float Bs[BK][TILE + 4];   // [kk][n]
    const int t  = threadIdx.x;
    const int tx = t & 15;
    const int ty = t >> 4;
    const int row0 = blockIdx.y * TILE;
    const int col0 = blockIdx.x * TILE;

    const int arow = t >> 2;           // 0..63
    const int akq  = (t & 3) * 4;      // 0,4,8,12
    const int brow = t >> 4;           // 0..15 (k within tile)
    const int bcol = (t & 15) * 4;     // 0..60

    float acc[4][4] = {};

    for (int k0 = 0; k0 < K; k0 += BK) {
        float4 av = *(const float4*)&A[(size_t)(row0 + arow) * K + k0 + akq];
        float4 bv = *(const float4*)&B[(size_t)(k0 + brow) * N + col0 + bcol];
        As[akq + 0][arow] = av.x;
        As[akq + 1][arow] = av.y;
        As[akq + 2][arow] = av.z;
        As[akq + 3][arow] = av.w;
        *(float4*)&Bs[brow][bcol] = bv;
        __syncthreads();
#pragma unroll
        for (int kk = 0; kk < BK; ++kk) {
            float4 a4 = *(const float4*)&As[kk][ty * 4];
            float4 b4 = *(const float4*)&Bs[kk][tx * 4];
            float a[4] = {a4.x, a4.y, a4.z, a4.w};
            float b[4] = {b4.x, b4.y, b4.z, b4.w};
#pragma unroll
            for (int i = 0; i < 4; ++i)
#pragma unroll
                for (int j = 0; j < 4; ++j)
                    acc[i][j] += a[i] * b[j];
        }
        __syncthreads();
    }
#pragma unroll
    for (int i = 0; i < 4; ++i) {
        float4 o = {acc[i][0], acc[i][1], acc[i][2], acc[i][3]};
        *(float4*)&C[(size_t)(row0 + ty * 4 + i) * N + col0 + tx * 4] = o;
    }
}

// ---------------------------------------------------------------------------
// Segment-masked attention, flash-style single pass over keys.
// qkv layout: [b*N rows][3072] = [ q(h*64+d) | k | v ].
// Block = 256 threads = 64 queries x 4 lanes; each lane owns 16 of 64 dims.
// Per key j: alpha = q.k (shfl-reduced over the 4-lane team), e = exp(alpha*s),
// seg = mask[b,i,j]; accumulate num[seg][d] += e*v, s[seg] += e.
// Epilogue: out = sum_seg num[seg] * (s>0 ? 1/s : 0)  -- matches the
// reference's fe / where(s==0,1,s) exactly (num==0 whenever s==0).
// ---------------------------------------------------------------------------
#define ATJ 64

__global__ __launch_bounds__(256) void attn_seg_fp32(const float* __restrict__ qkv,
                                                     const int* __restrict__ mask,
                                                     float* __restrict__ ctx) {
    __shared__ float Ks[ATJ][HDIM];     // 16 KB
    __shared__ float Vs[ATJ][HDIM];     // 16 KB
    __shared__ int   Ms[64][ATJ + 4];   // 17 KB; stride 68 ints: 2-way bank alias (free)

    const int t  = threadIdx.x;
    const int qi = t >> 2;           // query within tile: 0..63
    const int dq = (t & 3) * 16;     // this lane's dim slice
    const int i0 = blockIdx.x * 64;
    const int h  = blockIdx.y;
    const int b  = blockIdx.z;
    const float scale = 0.03125f;    // INTER^-0.5 = 1/32

    // q slice -> registers
    float qreg[16];
    {
        const float* qp = qkv + ((size_t)(b * NN + i0 + qi) * QKVW) + h * HDIM + dq;
#pragma unroll
        for (int c = 0; c < 4; ++c) {
            float4 v = *(const float4*)(qp + c * 4);
            qreg[c * 4 + 0] = v.x; qreg[c * 4 + 1] = v.y;
            qreg[c * 4 + 2] = v.z; qreg[c * 4 + 3] = v.w;
        }
    }

    float acc[NSEG][16] = {};
    float s[NSEG] = {0.f, 0.f, 0.f, 0.f};

    for (int j0 = 0; j0 < NN; j0 += ATJ) {
        // Stage K tile, V tile, mask tile (all float4/int4, coalesced)
#pragma unroll
        for (int c = 0; c < 4; ++c) {
            int idx4 = t + 256 * c;          // 0..1023
            int jj = idx4 >> 4;              // 0..63
            int dd = (idx4 & 15) * 4;        // 0..60
            const float* kp = qkv + ((size_t)(b * NN + j0 + jj) * QKVW) + INTER + h * HDIM + dd;
            *(float4*)&Ks[jj][dd] = *(const float4*)kp;
            *(float4*)&Vs[jj][dd] = *(const float4*)(kp + INTER);
            *(int4*)&Ms[jj][dd]   = *(const int4*)&mask[((size_t)(b * NN + i0 + jj)) * NN + j0 + dd];
        }
        __syncthreads();

        for (int jj = 0; jj < ATJ; ++jj) {
            float p = 0.f;
#pragma unroll
            for (int c = 0; c < 4; ++c) {
                float4 kv = *(const float4*)&Ks[jj][dq + c * 4];
                p += qreg[c * 4 + 0] * kv.x + qreg[c * 4 + 1] * kv.y
                   + qreg[c * 4 + 2] * kv.z + qreg[c * 4 + 3] * kv.w;
            }
            // reduce over the 4-lane team (lanes qi*4 .. qi*4+3)
            p += __shfl_xor(p, 1, 64);
            p += __shfl_xor(p, 2, 64);
            float e = __expf(p * scale);
            int seg = Ms[qi][jj];
            float w0 = (seg == 0) ? e : 0.f;
            float w1 = (seg == 1) ? e : 0.f;
            float w2 = (seg == 2) ? e : 0.f;
            float w3 = (seg == 3) ? e : 0.f;
            s[0] += w0; s[1] += w1; s[2] += w2; s[3] += w3;
#pragma unroll
            for (int c = 0; c < 4; ++c) {
                float4 vv = *(const float4*)&Vs[jj][dq + c * 4];
                float vl[4] = {vv.x, vv.y, vv.z, vv.w};
#pragma unroll
                for (int d = 0; d < 4; ++d) {
                    acc[0][c * 4 + d] += w0 * vl[d];
                    acc[1][c * 4 + d] += w1 * vl[d];
                    acc[2][c * 4 + d] += w2 * vl[d];
                    acc[3][c * 4 + d] += w3 * vl[d];
                }
            }
        }
        __syncthreads();
    }

    float r[NSEG];
#pragma unroll
    for (int k = 0; k < NSEG; ++k) r[k] = (s[k] > 0.f) ? (1.f / s[k]) : 0.f;

    float* op = ctx + ((size_t)(b * NN + i0 + qi) * INTER) + h * HDIM + dq;
#pragma unroll
    for (int c = 0; c < 4; ++c) {
        float4 o;
        o.x = acc[0][c*4+0]*r[0] + acc[1][c*4+0]*r[1] + acc[2][c*4+0]*r[2] + acc[3][c*4+0]*r[3];
        o.y = acc[0][c*4+1]*r[0] + acc[1][c*4+1]*r[1] + acc[2][c*4+1]*r[2] + acc[3][c*4+1]*r[3];
        o.z = acc[0][c*4+2]*r[0] + acc[1][c*4+2]*r[1] + acc[2][c*4+2]*r[2] + acc[3][c*4+2]*r[3];
        o.w = acc[0][c*4+3]*r[0] + acc[1][c*4+3]*r[1] + acc[2][c*4+3]*r[2] + acc[3][c*4+3]*r[3];
        *(float4*)(op + c * 4) = o;
    }
}

// ---------------------------------------------------------------------------
// Launch: qkv GEMM -> attention -> out GEMM. Workspace: qkv (50.3 MB) + ctx (16.8 MB).
// ---------------------------------------------------------------------------
extern "C" void kernel_launch(void* const* d_in, const int* in_sizes, int n_in,
                              void* d_out, int out_size, void* d_ws, size_t ws_size,
                              hipStream_t stream) {
    const float* features = (const float*)d_in[0];  // [B,N,DIM]
    const int*   mask     = (const int*)d_in[1];    // [B,N,N]
    const float* W_qkv    = (const float*)d_in[2];  // [DIM, 3*INTER]
    const float* W_out    = (const float*)d_in[3];  // [INTER, DIM]
    // d_in[4] = n_segments (always 4; compiled in)
    float* out = (float*)d_out;                     // [B,N,DIM]

    float* qkv = (float*)d_ws;                          // [B*N, 3072]
    float* ctx = qkv + (size_t)(BB * NN) * QKVW;        // [B*N, 1024]

    const int M = BB * NN;  // 4096
    dim3 blk(256);

    // 1) qkv = features @ W_qkv   [4096,1024] x [1024,3072]
    gemm_fp32<<<dim3(QKVW / TILE, M / TILE), blk, 0, stream>>>(
        features, W_qkv, qkv, M, QKVW, DIM);

    // 2) segment-masked attention -> ctx [4096,1024]
    attn_seg_fp32<<<dim3(NN / 64, NHEAD, BB), blk, 0, stream>>>(qkv, mask, ctx);

    // 3) out = ctx @ W_out        [4096,1024] x [1024,1024]
    gemm_fp32<<<dim3(DIM / TILE, M / TILE), blk, 0, stream>>>(
        ctx, W_out, out, M, DIM, INTER);
}

// Round 2
// 835.663 us; speedup vs baseline: 2.3477x; 2.3477x over previous
//
#include <hip/hip_runtime.h>
#include <hip/hip_bf16.h>

// Problem constants (reference: B=2, N=2048, DIM=1024, INTER=1024, HEAD=16, N_SEG=4)
#define BB 2
#define NN 2048
#define DIM 1024
#define INTER 1024
#define NHEAD 16
#define HDIM 64          // INTER / NHEAD
#define NSEG 4
#define QKVW (3 * INTER) // 3072

typedef __attribute__((ext_vector_type(8))) short bf16x8;
typedef __attribute__((ext_vector_type(4))) float f32x4;

static __device__ __forceinline__ unsigned short f2bf(float f) {
    __hip_bfloat16 h = __float2bfloat16(f);   // RNE
    return *reinterpret_cast<unsigned short*>(&h);
}

// ---------------------------------------------------------------------------
// Tiled fp32 GEMM: C[M,N] = A[M,K] @ B[K,N], row-major. 64x64 tile, BK=16.
// Round-1 measured: 131 TF fp32 = 83% of vector peak — keep as-is.
// ---------------------------------------------------------------------------
#define TILE 64
#define BK 16

__global__ __launch_bounds__(256) void gemm_fp32(const float* __restrict__ A,
                                                 const float* __restrict__ B,
                                                 float* __restrict__ C,
                                                 int M, int N, int K) {
    __shared__ float As[BK][TILE + 4];
    __shared__ float Bs[BK][TILE + 4];
    const int t  = threadIdx.x;
    const int tx = t & 15;
    const int ty = t >> 4;
    const int row0 = blockIdx.y * TILE;
    const int col0 = blockIdx.x * TILE;
    const int arow = t >> 2;
    const int akq  = (t & 3) * 4;
    const int brow = t >> 4;
    const int bcol = (t & 15) * 4;
    float acc[4][4] = {};
    for (int k0 = 0; k0 < K; k0 += BK) {
        float4 av = *(const float4*)&A[(size_t)(row0 + arow) * K + k0 + akq];
        float4 bv = *(const float4*)&B[(size_t)(k0 + brow) * N + col0 + bcol];
        As[akq + 0][arow] = av.x;
        As[akq + 1][arow] = av.y;
        As[akq + 2][arow] = av.z;
        As[akq + 3][arow] = av.w;
        *(float4*)&Bs[brow][bcol] = bv;
        __syncthreads();
#pragma unroll
        for (int kk = 0; kk < BK; ++kk) {
            float4 a4 = *(const float4*)&As[kk][ty * 4];
            float4 b4 = *(const float4*)&Bs[kk][tx * 4];
            float a[4] = {a4.x, a4.y, a4.z, a4.w};
            float b[4] = {b4.x, b4.y, b4.z, b4.w};
#pragma unroll
            for (int i = 0; i < 4; ++i)
#pragma unroll
                for (int j = 0; j < 4; ++j)
                    acc[i][j] += a[i] * b[j];
        }
        __syncthreads();
    }
#pragma unroll
    for (int i = 0; i < 4; ++i) {
        float4 o = {acc[i][0], acc[i][1], acc[i][2], acc[i][3]};
        *(float4*)&C[(size_t)(row0 + ty * 4 + i) * N + col0 + tx * 4] = o;
    }
}

// Same GEMM but stores bf16 (for qkv: everything downstream feeds bf16 MFMA).
__global__ __launch_bounds__(256) void gemm_fp32_bf16out(const float* __restrict__ A,
                                                         const float* __restrict__ B,
                                                         unsigned short* __restrict__ C,
                                                         int M, int N, int K) {
    __shared__ float As[BK][TILE + 4];
    __shared__ float Bs[BK][TILE + 4];
    const int t  = threadIdx.x;
    const int tx = t & 15;
    const int ty = t >> 4;
    const int row0 = blockIdx.y * TILE;
    const int col0 = blockIdx.x * TILE;
    const int arow = t >> 2;
    const int akq  = (t & 3) * 4;
    const int brow = t >> 4;
    const int bcol = (t & 15) * 4;
    float acc[4][4] = {};
    for (int k0 = 0; k0 < K; k0 += BK) {
        float4 av = *(const float4*)&A[(size_t)(row0 + arow) * K + k0 + akq];
        float4 bv = *(const float4*)&B[(size_t)(k0 + brow) * N + col0 + bcol];
        As[akq + 0][arow] = av.x;
        As[akq + 1][arow] = av.y;
        As[akq + 2][arow] = av.z;
        As[akq + 3][arow] = av.w;
        *(float4*)&Bs[brow][bcol] = bv;
        __syncthreads();
#pragma unroll
        for (int kk = 0; kk < BK; ++kk) {
            float4 a4 = *(const float4*)&As[kk][ty * 4];
            float4 b4 = *(const float4*)&Bs[kk][tx * 4];
            float a[4] = {a4.x, a4.y, a4.z, a4.w};
            float b[4] = {b4.x, b4.y, b4.z, b4.w};
#pragma unroll
            for (int i = 0; i < 4; ++i)
#pragma unroll
                for (int j = 0; j < 4; ++j)
                    acc[i][j] += a[i] * b[j];
        }
        __syncthreads();
    }
#pragma unroll
    for (int i = 0; i < 4; ++i) {
        ushort4 o = {f2bf(acc[i][0]), f2bf(acc[i][1]), f2bf(acc[i][2]), f2bf(acc[i][3])};
        *(ushort4*)&C[(size_t)(row0 + ty * 4 + i) * N + col0 + tx * 4] = o;
    }
}

// ---------------------------------------------------------------------------
// Segment-masked attention, MFMA (bf16), single sweep over keys.
// Block = 4 waves; Q-tile = 64 rows (wave w owns rows 16w..16w+15). Per 64-key
// tile: E = exp(scale*Q@K^T) via 8 MFMAs; E -> LDS (C-layout -> A-layout
// transform, m120 pattern); per segment m: W_m = E & [seg==m] (bitwise mask on
// bf16 bits), 4 dense PV MFMAs + 1 ones-column MFMA (denominator tile; B-frag
// is a compile-time constant). Epilogue: out = sum_m acc_m * (s_m>0 ? 1/s_m:0)
// == reference's fe/where(s==0,1,s) since acc_m==0 whenever s_m==0.
// MFMA layouts (16x16x32, m89/m91-verified): C/D col=lane&15,row=quad*4+reg;
// A[m=lane&15][k=quad*8+j]; B[k=quad*8+j][n=lane&15].
// ---------------------------------------------------------------------------
__global__ __launch_bounds__(256, 3) void attn_seg_mfma(
        const unsigned short* __restrict__ qkv,   // bf16 [B*N][3072] = q|k|v
        const int* __restrict__ mask,             // [B,N,N]
        float* __restrict__ ctx) {                // [B*N][INTER]
    __shared__ __align__(16) unsigned short Ks[64][72];  // [key][dim]  9216 B
    __shared__ __align__(16) unsigned short Vt[64][72];  // [dim][key]  9216 B (transposed!)
    __shared__ __align__(16) unsigned char  Mb[64][72];  // [row][key]  4608 B (seg ids)
    __shared__ __align__(16) unsigned short El[4][16][88]; // per-wave E tile 11264 B
    // strides 72/88: multiples of 8 bf16 keep 16B alignment for ds_read_b128;
    // 88 breaks the worst write conflicts on El (4-way, ~free).

    const int t    = threadIdx.x;
    const int w    = t >> 6;          // wave 0..3
    const int lane = t & 63;
    const int l15  = lane & 15;
    const int quad = lane >> 4;
    const int i0   = blockIdx.x * 64;
    const int h    = blockIdx.y;
    const int b    = blockIdx.z;

    // Q A-fragments (fixed for the whole sweep)
    bf16x8 qa0, qa1;
    {
        const unsigned short* qp =
            qkv + (size_t)(b * NN + i0 + w * 16 + l15) * QKVW + h * HDIM + quad * 8;
        qa0 = *(const bf16x8*)qp;
        qa1 = *(const bf16x8*)(qp + 32);
    }

    // ones B-fragment: B[k][0] = 1.0 -> denominator lands in col 0 of tile 4
    bf16x8 onesb;
    {
        short ob = (l15 == 0) ? (short)0x3F80 : (short)0;
#pragma unroll
        for (int j = 0; j < 8; ++j) onesb[j] = ob;
    }

    f32x4 acc[NSEG][5];   // [segment][ntile]; ntile 4 = denominator
#pragma unroll
    for (int m = 0; m < NSEG; ++m)
#pragma unroll
        for (int nt = 0; nt < 5; ++nt) acc[m][nt] = (f32x4){0.f, 0.f, 0.f, 0.f};

    for (int j0 = 0; j0 < NN; j0 += 64) {
        // ---- stage K (b128), V transposed (gather-by-dim), mask (int8) ----
#pragma unroll
        for (int it = 0; it < 2; ++it) {
            int id  = t + it * 256;
            int key = id >> 3;
            int dc  = (id & 7) * 8;
            const unsigned short* kp =
                qkv + (size_t)(b * NN + j0 + key) * QKVW + INTER + h * HDIM + dc;
            *(bf16x8*)&Ks[key][dc] = *(const bf16x8*)kp;
        }
        {
            int dmy = t & 63;       // this thread's dim; wave reads 128B rows coalesced
            int g0  = t >> 6;
#pragma unroll
            for (int it = 0; it < 2; ++it) {
                int g = g0 + it * 4;          // key group 0..7 (8 keys each)
                unsigned short tmp[8];
#pragma unroll
                for (int j = 0; j < 8; ++j)
                    tmp[j] = qkv[(size_t)(b * NN + j0 + g * 8 + j) * QKVW + 2 * INTER + h * HDIM + dmy];
                *(bf16x8*)&Vt[dmy][g * 8] = *(const bf16x8*)tmp;
            }
        }
#pragma unroll
        for (int it = 0; it < 4; ++it) {
            int id  = t + it * 256;
            int row = id >> 4;
            int c4  = (id & 15) * 4;
            int4 mv = *(const int4*)&mask[(size_t)(b * NN + i0 + row) * NN + j0 + c4];
            unsigned int p = (unsigned int)(mv.x & 3) | ((unsigned int)(mv.y & 3) << 8) |
                             ((unsigned int)(mv.z & 3) << 16) | ((unsigned int)(mv.w & 3) << 24);
            *(unsigned int*)&Mb[row][c4] = p;
        }
        __syncthreads();

        // ---- E = exp(scale * Q K^T) -> El (per-wave private; same-wave DS ops
        //      are processed in order, so no barrier before the A-frag reads) ----
#pragma unroll
        for (int nt = 0; nt < 4; ++nt) {
            f32x4 s = {0.f, 0.f, 0.f, 0.f};
            bf16x8 kb0 = *(const bf16x8*)&Ks[nt * 16 + l15][quad * 8];
            bf16x8 kb1 = *(const bf16x8*)&Ks[nt * 16 + l15][32 + quad * 8];
            s = __builtin_amdgcn_mfma_f32_16x16x32_bf16(qa0, kb0, s, 0, 0, 0);
            s = __builtin_amdgcn_mfma_f32_16x16x32_bf16(qa1, kb1, s, 0, 0, 0);
#pragma unroll
            for (int r = 0; r < 4; ++r) {
                float e = __expf(s[r] * 0.03125f);   // scale = INTER^-0.5 = 1/32
                El[w][quad * 4 + r][nt * 16 + l15] = f2bf(e);
            }
        }

        // ---- PV: per k-step read E A-frag + seg bytes + V B-frags, then 4
        //      masked A variants x (4 dim tiles + ones tile) ----
#pragma unroll
        for (int ks = 0; ks < 2; ++ks) {
            union { int4 i; bf16x8 v; } ef;
            ef.i = *(const int4*)&El[w][l15][ks * 32 + quad * 8];
            uint2 sbv = *(const uint2*)&Mb[w * 16 + l15][ks * 32 + quad * 8];
            unsigned int segb[8];
            segb[0] = sbv.x & 0xFF;  segb[1] = (sbv.x >> 8) & 0xFF;
            segb[2] = (sbv.x >> 16) & 0xFF; segb[3] = sbv.x >> 24;
            segb[4] = sbv.y & 0xFF;  segb[5] = (sbv.y >> 8) & 0xFF;
            segb[6] = (sbv.y >> 16) & 0xFF; segb[7] = sbv.y >> 24;
            bf16x8 vb[4];
#pragma unroll
            for (int nt = 0; nt < 4; ++nt)
                vb[nt] = *(const bf16x8*)&Vt[nt * 16 + l15][ks * 32 + quad * 8];
#pragma unroll
            for (int m = 0; m < NSEG; ++m) {
                union { int4 i; bf16x8 v; } wm;
#pragma unroll
                for (int d = 0; d < 4; ++d) {
                    unsigned int mk = (segb[2 * d] == (unsigned)m ? 0x0000FFFFu : 0u) |
                                      (segb[2 * d + 1] == (unsigned)m ? 0xFFFF0000u : 0u);
                    ((unsigned int*)&wm.i)[d] = ((const unsigned int*)&ef.i)[d] & mk;
                }
#pragma unroll
                for (int nt = 0; nt < 4; ++nt)
                    acc[m][nt] = __builtin_amdgcn_mfma_f32_16x16x32_bf16(wm.v, vb[nt], acc[m][nt], 0, 0, 0);
                acc[m][4] = __builtin_amdgcn_mfma_f32_16x16x32_bf16(wm.v, onesb, acc[m][4], 0, 0, 0);
            }
        }
        __syncthreads();
    }

    // ---- epilogue: r = 1/s per (segment, row); out = sum_m acc_m * r_m ----
    float rres[NSEG][4];
#pragma unroll
    for (int m = 0; m < NSEG; ++m)
#pragma unroll
        for (int r = 0; r < 4; ++r) {
            float sum = __shfl(acc[m][4][r], lane & 48, 64);  // col-0 lane of my quad
            rres[m][r] = (sum > 0.f) ? (1.f / sum) : 0.f;
        }
#pragma unroll
    for (int nt = 0; nt < 4; ++nt)
#pragma unroll
        for (int r = 0; r < 4; ++r) {
            float v = acc[0][nt][r] * rres[0][r] + acc[1][nt][r] * rres[1][r] +
                      acc[2][nt][r] * rres[2][r] + acc[3][nt][r] * rres[3][r];
            ctx[(size_t)(b * NN + i0 + w * 16 + quad * 4 + r) * INTER + h * HDIM + nt * 16 + l15] = v;
        }
}

// ---------------------------------------------------------------------------
extern "C" void kernel_launch(void* const* d_in, const int* in_sizes, int n_in,
                              void* d_out, int out_size, void* d_ws, size_t ws_size,
                              hipStream_t stream) {
    const float* features = (const float*)d_in[0];
    const int*   mask     = (const int*)d_in[1];
    const float* W_qkv    = (const float*)d_in[2];
    const float* W_out    = (const float*)d_in[3];
    float* out = (float*)d_out;

    unsigned short* qkvb = (unsigned short*)d_ws;                       // bf16 [4096][3072], 25.2 MB
    float* ctx = (float*)((char*)d_ws + (size_t)BB * NN * QKVW * 2);    // fp32 [4096][1024], 16.8 MB

    const int M = BB * NN;
    dim3 blk(256);

    gemm_fp32_bf16out<<<dim3(QKVW / TILE, M / TILE), blk, 0, stream>>>(
        features, W_qkv, qkvb, M, QKVW, DIM);

    attn_seg_mfma<<<dim3(NN / 64, NHEAD, BB), blk, 0, stream>>>(qkvb, mask, ctx);

    gemm_fp32<<<dim3(DIM / TILE, M / TILE), blk, 0, stream>>>(
        ctx, W_out, out, M, DIM, INTER);
}

// Round 3
// 553.920 us; speedup vs baseline: 3.5418x; 1.5086x over previous
//
#include <hip/hip_runtime.h>
#include <hip/hip_bf16.h>

// Problem constants (reference: B=2, N=2048, DIM=1024, INTER=1024, HEAD=16, N_SEG=4)
#define BB 2
#define NN 2048
#define DIM 1024
#define INTER 1024
#define NHEAD 16
#define HDIM 64          // INTER / NHEAD
#define NSEG 4
#define QKVW (3 * INTER) // 3072

typedef __attribute__((ext_vector_type(8))) short bf16x8;
typedef __attribute__((ext_vector_type(4))) float f32x4;

static __device__ __forceinline__ unsigned short f2bf(float f) {
    __hip_bfloat16 h = __float2bfloat16(f);   // RNE
    return *reinterpret_cast<unsigned short*>(&h);
}

// ---------------------------------------------------------------------------
// Prepass: fp32 -> bf16 elementwise (features). n must be /1024.
// ---------------------------------------------------------------------------
__global__ __launch_bounds__(256) void conv_f32_bf16(const float* __restrict__ in,
                                                     unsigned short* __restrict__ out) {
    int i = (blockIdx.x * 256 + threadIdx.x) * 4;
    float4 v = *(const float4*)&in[i];
    ushort4 o = {f2bf(v.x), f2bf(v.y), f2bf(v.z), f2bf(v.w)};
    *(ushort4*)&out[i] = o;
}

// ---------------------------------------------------------------------------
// Prepass: convert + transpose  in[R][C] fp32  ->  out[C][R] bf16.
// 64x64 tile per 256-thread block; LDS stride 65 keeps column reads 2-way (free).
// ---------------------------------------------------------------------------
__global__ __launch_bounds__(256) void transp_f32_bf16(const float* __restrict__ in,
                                                       unsigned short* __restrict__ out,
                                                       int R, int C) {
    __shared__ float tile[64][65];
    const int r0 = blockIdx.y * 64, c0 = blockIdx.x * 64;
    const int t = threadIdx.x;
#pragma unroll
    for (int it = 0; it < 4; ++it) {
        int r = it * 16 + (t >> 4);
        int c = (t & 15) * 4;
        float4 v = *(const float4*)&in[(size_t)(r0 + r) * C + c0 + c];
        tile[r][c] = v.x; tile[r][c + 1] = v.y; tile[r][c + 2] = v.z; tile[r][c + 3] = v.w;
    }
    __syncthreads();
#pragma unroll
    for (int it = 0; it < 4; ++it) {
        int c = it * 16 + (t >> 4);   // output row (= original col)
        int r = (t & 15) * 4;         // output col base (= original row)
        ushort4 o = {f2bf(tile[r][c]), f2bf(tile[r + 1][c]), f2bf(tile[r + 2][c]), f2bf(tile[r + 3][c])};
        *(ushort4*)&out[(size_t)(c0 + c) * R + r0 + r] = o;
    }
}

// ---------------------------------------------------------------------------
// bf16 MFMA GEMM (m97 structure): C[M][N] = A[M][K] @ Bt[N][K]^T, bf16 out.
// 128x128 tile / 256 threads; wave w owns 64x64 (wr=w>>1, wc=w&1), 4x4 grid of
// 16x16x32 MFMAs; BK=32; staging via global_load_lds width=16 (lane l of wave
// lands at ldsbase + l*16 -> 4 lanes per 32-elem row, [row][k] layout).
// ---------------------------------------------------------------------------
#define GBK 32

__global__ __launch_bounds__(256) void gemm_bf16_mfma(
        const unsigned short* __restrict__ A,   // [M][K] bf16
        const unsigned short* __restrict__ Bt,  // [N][K] bf16
        unsigned short* __restrict__ C,         // [M][N] bf16
        int M, int N, int K) {
    __shared__ __align__(16) unsigned short As[128][GBK];  // 8 KB
    __shared__ __align__(16) unsigned short Bs[128][GBK];  // 8 KB
    const int t = threadIdx.x;
    const int w = t >> 6, lane = t & 63, l15 = lane & 15, quad = lane >> 4;
    const int wr = w >> 1, wc = w & 1;
    const int row0 = blockIdx.y * 128, col0 = blockIdx.x * 128;
    const int lrow = lane >> 2;        // 0..15
    const int lkof = (lane & 3) * 8;   // 0,8,16,24

    f32x4 acc[4][4];
#pragma unroll
    for (int i = 0; i < 4; ++i)
#pragma unroll
        for (int j = 0; j < 4; ++j) acc[i][j] = (f32x4){0.f, 0.f, 0.f, 0.f};

    for (int k0 = 0; k0 < K; k0 += GBK) {
#pragma unroll
        for (int c = 0; c < 2; ++c) {
            int rbase = w * 32 + c * 16;   // wave-uniform
            const unsigned short* ga = A  + (size_t)(row0 + rbase + lrow) * K + k0 + lkof;
            const unsigned short* gb = Bt + (size_t)(col0 + rbase + lrow) * K + k0 + lkof;
            __builtin_amdgcn_global_load_lds(
                (const __attribute__((address_space(1))) void*)ga,
                (__attribute__((address_space(3))) void*)&As[rbase][0], 16, 0, 0);
            __builtin_amdgcn_global_load_lds(
                (const __attribute__((address_space(1))) void*)gb,
                (__attribute__((address_space(3))) void*)&Bs[rbase][0], 16, 0, 0);
        }
        __syncthreads();
        bf16x8 af[4], bfr[4];
#pragma unroll
        for (int i = 0; i < 4; ++i) af[i]  = *(const bf16x8*)&As[wr * 64 + i * 16 + l15][quad * 8];
#pragma unroll
        for (int j = 0; j < 4; ++j) bfr[j] = *(const bf16x8*)&Bs[wc * 64 + j * 16 + l15][quad * 8];
#pragma unroll
        for (int i = 0; i < 4; ++i)
#pragma unroll
            for (int j = 0; j < 4; ++j)
                acc[i][j] = __builtin_amdgcn_mfma_f32_16x16x32_bf16(af[i], bfr[j], acc[i][j], 0, 0, 0);
        __syncthreads();
    }
#pragma unroll
    for (int i = 0; i < 4; ++i)
#pragma unroll
        for (int j = 0; j < 4; ++j)
#pragma unroll
            for (int r = 0; r < 4; ++r) {
                int row = row0 + wr * 64 + i * 16 + quad * 4 + r;
                int col = col0 + wc * 64 + j * 16 + l15;
                C[(size_t)row * N + col] = f2bf(acc[i][j][r]);
            }
}

// ---------------------------------------------------------------------------
// Tiled fp32 GEMM (out-projection): measured 131 TF = 83% of vector peak.
// ---------------------------------------------------------------------------
#define TILE 64
#define BK 16

__global__ __launch_bounds__(256) void gemm_fp32(const float* __restrict__ A,
                                                 const float* __restrict__ B,
                                                 float* __restrict__ C,
                                                 int M, int N, int K) {
    __shared__ float As[BK][TILE + 4];
    __shared__ float Bs[BK][TILE + 4];
    const int t  = threadIdx.x;
    const int tx = t & 15;
    const int ty = t >> 4;
    const int row0 = blockIdx.y * TILE;
    const int col0 = blockIdx.x * TILE;
    const int arow = t >> 2;
    const int akq  = (t & 3) * 4;
    const int brow = t >> 4;
    const int bcol = (t & 15) * 4;
    float acc[4][4] = {};
    for (int k0 = 0; k0 < K; k0 += BK) {
        float4 av = *(const float4*)&A[(size_t)(row0 + arow) * K + k0 + akq];
        float4 bv = *(const float4*)&B[(size_t)(k0 + brow) * N + col0 + bcol];
        As[akq + 0][arow] = av.x;
        As[akq + 1][arow] = av.y;
        As[akq + 2][arow] = av.z;
        As[akq + 3][arow] = av.w;
        *(float4*)&Bs[brow][bcol] = bv;
        __syncthreads();
#pragma unroll
        for (int kk = 0; kk < BK; ++kk) {
            float4 a4 = *(const float4*)&As[kk][ty * 4];
            float4 b4 = *(const float4*)&Bs[kk][tx * 4];
            float a[4] = {a4.x, a4.y, a4.z, a4.w};
            float b[4] = {b4.x, b4.y, b4.z, b4.w};
#pragma unroll
            for (int i = 0; i < 4; ++i)
#pragma unroll
                for (int j = 0; j < 4; ++j)
                    acc[i][j] += a[i] * b[j];
        }
        __syncthreads();
    }
#pragma unroll
    for (int i = 0; i < 4; ++i) {
        float4 o = {acc[i][0], acc[i][1], acc[i][2], acc[i][3]};
        *(float4*)&C[(size_t)(row0 + ty * 4 + i) * N + col0 + tx * 4] = o;
    }
}

// ---------------------------------------------------------------------------
// Segment-masked attention, MFMA (bf16), single sweep over keys. (Unchanged
// from round 2 — passed at absmax 9.8e-4; counters land next round.)
// ---------------------------------------------------------------------------
__global__ __launch_bounds__(256, 3) void attn_seg_mfma(
        const unsigned short* __restrict__ qkv,   // bf16 [B*N][3072] = q|k|v
        const int* __restrict__ mask,             // [B,N,N]
        float* __restrict__ ctx) {                // [B*N][INTER]
    __shared__ __align__(16) unsigned short Ks[64][72];
    __shared__ __align__(16) unsigned short Vt[64][72];
    __shared__ __align__(16) unsigned char  Mb[64][72];
    __shared__ __align__(16) unsigned short El[4][16][88];

    const int t    = threadIdx.x;
    const int w    = t >> 6;
    const int lane = t & 63;
    const int l15  = lane & 15;
    const int quad = lane >> 4;
    const int i0   = blockIdx.x * 64;
    const int h    = blockIdx.y;
    const int b    = blockIdx.z;

    bf16x8 qa0, qa1;
    {
        const unsigned short* qp =
            qkv + (size_t)(b * NN + i0 + w * 16 + l15) * QKVW + h * HDIM + quad * 8;
        qa0 = *(const bf16x8*)qp;
        qa1 = *(const bf16x8*)(qp + 32);
    }

    bf16x8 onesb;
    {
        short ob = (l15 == 0) ? (short)0x3F80 : (short)0;
#pragma unroll
        for (int j = 0; j < 8; ++j) onesb[j] = ob;
    }

    f32x4 acc[NSEG][5];
#pragma unroll
    for (int m = 0; m < NSEG; ++m)
#pragma unroll
        for (int nt = 0; nt < 5; ++nt) acc[m][nt] = (f32x4){0.f, 0.f, 0.f, 0.f};

    for (int j0 = 0; j0 < NN; j0 += 64) {
#pragma unroll
        for (int it = 0; it < 2; ++it) {
            int id  = t + it * 256;
            int key = id >> 3;
            int dc  = (id & 7) * 8;
            const unsigned short* kp =
                qkv + (size_t)(b * NN + j0 + key) * QKVW + INTER + h * HDIM + dc;
            *(bf16x8*)&Ks[key][dc] = *(const bf16x8*)kp;
        }
        {
            int dmy = t & 63;
            int g0  = t >> 6;
#pragma unroll
            for (int it = 0; it < 2; ++it) {
                int g = g0 + it * 4;
                unsigned short tmp[8];
#pragma unroll
                for (int j = 0; j < 8; ++j)
                    tmp[j] = qkv[(size_t)(b * NN + j0 + g * 8 + j) * QKVW + 2 * INTER + h * HDIM + dmy];
                *(bf16x8*)&Vt[dmy][g * 8] = *(const bf16x8*)tmp;
            }
        }
#pragma unroll
        for (int it = 0; it < 4; ++it) {
            int id  = t + it * 256;
            int row = id >> 4;
            int c4  = (id & 15) * 4;
            int4 mv = *(const int4*)&mask[(size_t)(b * NN + i0 + row) * NN + j0 + c4];
            unsigned int p = (unsigned int)(mv.x & 3) | ((unsigned int)(mv.y & 3) << 8) |
                             ((unsigned int)(mv.z & 3) << 16) | ((unsigned int)(mv.w & 3) << 24);
            *(unsigned int*)&Mb[row][c4] = p;
        }
        __syncthreads();

#pragma unroll
        for (int nt = 0; nt < 4; ++nt) {
            f32x4 s = {0.f, 0.f, 0.f, 0.f};
            bf16x8 kb0 = *(const bf16x8*)&Ks[nt * 16 + l15][quad * 8];
            bf16x8 kb1 = *(const bf16x8*)&Ks[nt * 16 + l15][32 + quad * 8];
            s = __builtin_amdgcn_mfma_f32_16x16x32_bf16(qa0, kb0, s, 0, 0, 0);
            s = __builtin_amdgcn_mfma_f32_16x16x32_bf16(qa1, kb1, s, 0, 0, 0);
#pragma unroll
            for (int r = 0; r < 4; ++r) {
                float e = __expf(s[r] * 0.03125f);
                El[w][quad * 4 + r][nt * 16 + l15] = f2bf(e);
            }
        }

#pragma unroll
        for (int ks = 0; ks < 2; ++ks) {
            union { int4 i; bf16x8 v; } ef;
            ef.i = *(const int4*)&El[w][l15][ks * 32 + quad * 8];
            uint2 sbv = *(const uint2*)&Mb[w * 16 + l15][ks * 32 + quad * 8];
            unsigned int segb[8];
            segb[0] = sbv.x & 0xFF;  segb[1] = (sbv.x >> 8) & 0xFF;
            segb[2] = (sbv.x >> 16) & 0xFF; segb[3] = sbv.x >> 24;
            segb[4] = sbv.y & 0xFF;  segb[5] = (sbv.y >> 8) & 0xFF;
            segb[6] = (sbv.y >> 16) & 0xFF; segb[7] = sbv.y >> 24;
            bf16x8 vb[4];
#pragma unroll
            for (int nt = 0; nt < 4; ++nt)
                vb[nt] = *(const bf16x8*)&Vt[nt * 16 + l15][ks * 32 + quad * 8];
#pragma unroll
            for (int m = 0; m < NSEG; ++m) {
                union { int4 i; bf16x8 v; } wm;
#pragma unroll
                for (int d = 0; d < 4; ++d) {
                    unsigned int mk = (segb[2 * d] == (unsigned)m ? 0x0000FFFFu : 0u) |
                                      (segb[2 * d + 1] == (unsigned)m ? 0xFFFF0000u : 0u);
                    ((unsigned int*)&wm.i)[d] = ((const unsigned int*)&ef.i)[d] & mk;
                }
#pragma unroll
                for (int nt = 0; nt < 4; ++nt)
                    acc[m][nt] = __builtin_amdgcn_mfma_f32_16x16x32_bf16(wm.v, vb[nt], acc[m][nt], 0, 0, 0);
                acc[m][4] = __builtin_amdgcn_mfma_f32_16x16x32_bf16(wm.v, onesb, acc[m][4], 0, 0, 0);
            }
        }
        __syncthreads();
    }

    float rres[NSEG][4];
#pragma unroll
    for (int m = 0; m < NSEG; ++m)
#pragma unroll
        for (int r = 0; r < 4; ++r) {
            float sum = __shfl(acc[m][4][r], lane & 48, 64);
            rres[m][r] = (sum > 0.f) ? (1.f / sum) : 0.f;
        }
#pragma unroll
    for (int nt = 0; nt < 4; ++nt)
#pragma unroll
        for (int r = 0; r < 4; ++r) {
            float v = acc[0][nt][r] * rres[0][r] + acc[1][nt][r] * rres[1][r] +
                      acc[2][nt][r] * rres[2][r] + acc[3][nt][r] * rres[3][r];
            ctx[(size_t)(b * NN + i0 + w * 16 + quad * 4 + r) * INTER + h * HDIM + nt * 16 + l15] = v;
        }
}

// ---------------------------------------------------------------------------
extern "C" void kernel_launch(void* const* d_in, const int* in_sizes, int n_in,
                              void* d_out, int out_size, void* d_ws, size_t ws_size,
                              hipStream_t stream) {
    const float* features = (const float*)d_in[0];  // [B,N,DIM] fp32
    const int*   mask     = (const int*)d_in[1];    // [B,N,N]
    const float* W_qkv    = (const float*)d_in[2];  // [DIM, 3*INTER] fp32
    const float* W_out    = (const float*)d_in[3];  // [INTER, DIM] fp32
    float* out = (float*)d_out;                     // [B,N,DIM] fp32

    const int M = BB * NN;  // 4096
    char* ws = (char*)d_ws;
    unsigned short* qkvb = (unsigned short*)ws;                 // bf16 [4096][3072] 25.2 MB
    ws += (size_t)M * QKVW * 2;
    float* ctx = (float*)ws;                                    // fp32 [4096][1024] 16.8 MB
    ws += (size_t)M * INTER * 4;
    unsigned short* featb = (unsigned short*)ws;                // bf16 [4096][1024] 8.4 MB
    ws += (size_t)M * DIM * 2;
    unsigned short* wqt = (unsigned short*)ws;                  // bf16 [3072][1024] 6.3 MB

    dim3 blk(256);

    // Prepass: features -> bf16; W_qkv -> bf16 transposed [3072][1024]
    conv_f32_bf16<<<dim3((M * DIM) / 1024), blk, 0, stream>>>(features, featb);
    transp_f32_bf16<<<dim3(QKVW / 64, DIM / 64), blk, 0, stream>>>(W_qkv, wqt, DIM, QKVW);

    // 1) qkv = features @ W_qkv  via bf16 MFMA (m97 structure)
    gemm_bf16_mfma<<<dim3(QKVW / 128, M / 128), blk, 0, stream>>>(
        featb, wqt, qkvb, M, QKVW, DIM);

    // 2) segment-masked attention -> ctx
    attn_seg_mfma<<<dim3(NN / 64, NHEAD, BB), blk, 0, stream>>>(qkvb, mask, ctx);

    // 3) out = ctx @ W_out (fp32, exact)
    gemm_fp32<<<dim3(DIM / TILE, M / TILE), blk, 0, stream>>>(
        ctx, W_out, out, M, DIM, INTER);
}

// Round 4
// 399.902 us; speedup vs baseline: 4.9058x; 1.3851x over previous
//
#include <hip/hip_runtime.h>
#include <hip/hip_bf16.h>

// Problem constants (reference: B=2, N=2048, DIM=1024, INTER=1024, HEAD=16, N_SEG=4)
#define BB 2
#define NN 2048
#define DIM 1024
#define INTER 1024
#define NHEAD 16
#define HDIM 64          // INTER / NHEAD
#define NSEG 4
#define QKVW (3 * INTER) // 3072

typedef __attribute__((ext_vector_type(8))) short bf16x8;
typedef __attribute__((ext_vector_type(4))) float f32x4;

static __device__ __forceinline__ unsigned short f2bf(float f) {
    __hip_bfloat16 h = __float2bfloat16(f);   // RNE
    return *reinterpret_cast<unsigned short*>(&h);
}

// ---------------------------------------------------------------------------
// Prepass: fp32 -> bf16 elementwise (features). n must be /1024.
// ---------------------------------------------------------------------------
__global__ __launch_bounds__(256) void conv_f32_bf16(const float* __restrict__ in,
                                                     unsigned short* __restrict__ out) {
    int i = (blockIdx.x * 256 + threadIdx.x) * 4;
    float4 v = *(const float4*)&in[i];
    ushort4 o = {f2bf(v.x), f2bf(v.y), f2bf(v.z), f2bf(v.w)};
    *(ushort4*)&out[i] = o;
}

// ---------------------------------------------------------------------------
// Prepass: convert + transpose  in[R][C] fp32  ->  out[C][R] bf16.
// ---------------------------------------------------------------------------
__global__ __launch_bounds__(256) void transp_f32_bf16(const float* __restrict__ in,
                                                       unsigned short* __restrict__ out,
                                                       int R, int C) {
    __shared__ float tile[64][65];
    const int r0 = blockIdx.y * 64, c0 = blockIdx.x * 64;
    const int t = threadIdx.x;
#pragma unroll
    for (int it = 0; it < 4; ++it) {
        int r = it * 16 + (t >> 4);
        int c = (t & 15) * 4;
        float4 v = *(const float4*)&in[(size_t)(r0 + r) * C + c0 + c];
        tile[r][c] = v.x; tile[r][c + 1] = v.y; tile[r][c + 2] = v.z; tile[r][c + 3] = v.w;
    }
    __syncthreads();
#pragma unroll
    for (int it = 0; it < 4; ++it) {
        int c = it * 16 + (t >> 4);
        int r = (t & 15) * 4;
        ushort4 o = {f2bf(tile[r][c]), f2bf(tile[r + 1][c]), f2bf(tile[r + 2][c]), f2bf(tile[r + 3][c])};
        *(ushort4*)&out[(size_t)(c0 + c) * R + r0 + r] = o;
    }
}

// ---------------------------------------------------------------------------
// QKV GEMM, bf16 MFMA (m97 structure): [4096][1024] @ [3072][1024]^T.
// q|k columns (col<2048) -> Cqk [4096][2048]; v columns -> Vtg transposed
// [b][h*64+d][n] (C-frag rows are contiguous along n -> ushort4 stores),
// so attention can stage V with coalesced b128 loads (kills the V-gather).
// ---------------------------------------------------------------------------
#define GBK 32

__global__ __launch_bounds__(256) void gemm_qkv_mfma(
        const unsigned short* __restrict__ A,    // [4096][1024] bf16
        const unsigned short* __restrict__ Bt,   // [3072][1024] bf16
        unsigned short* __restrict__ Cqk,        // [4096][2048] bf16 (q|k)
        unsigned short* __restrict__ Vtg) {      // [2][1024][2048] bf16
    const int K = 1024;
    __shared__ __align__(16) unsigned short As[128][GBK];
    __shared__ __align__(16) unsigned short Bs[128][GBK];
    const int t = threadIdx.x;
    const int w = t >> 6, lane = t & 63, l15 = lane & 15, quad = lane >> 4;
    const int wr = w >> 1, wc = w & 1;
    const int row0 = blockIdx.y * 128, col0 = blockIdx.x * 128;
    const int lrow = lane >> 2;
    const int lkof = (lane & 3) * 8;

    f32x4 acc[4][4];
#pragma unroll
    for (int i = 0; i < 4; ++i)
#pragma unroll
        for (int j = 0; j < 4; ++j) acc[i][j] = (f32x4){0.f, 0.f, 0.f, 0.f};

    for (int k0 = 0; k0 < K; k0 += GBK) {
#pragma unroll
        for (int c = 0; c < 2; ++c) {
            int rbase = w * 32 + c * 16;
            const unsigned short* ga = A  + (size_t)(row0 + rbase + lrow) * K + k0 + lkof;
            const unsigned short* gb = Bt + (size_t)(col0 + rbase + lrow) * K + k0 + lkof;
            __builtin_amdgcn_global_load_lds(
                (const __attribute__((address_space(1))) void*)ga,
                (__attribute__((address_space(3))) void*)&As[rbase][0], 16, 0, 0);
            __builtin_amdgcn_global_load_lds(
                (const __attribute__((address_space(1))) void*)gb,
                (__attribute__((address_space(3))) void*)&Bs[rbase][0], 16, 0, 0);
        }
        __syncthreads();
        bf16x8 af[4], bfr[4];
#pragma unroll
        for (int i = 0; i < 4; ++i) af[i]  = *(const bf16x8*)&As[wr * 64 + i * 16 + l15][quad * 8];
#pragma unroll
        for (int j = 0; j < 4; ++j) bfr[j] = *(const bf16x8*)&Bs[wc * 64 + j * 16 + l15][quad * 8];
#pragma unroll
        for (int i = 0; i < 4; ++i)
#pragma unroll
            for (int j = 0; j < 4; ++j)
                acc[i][j] = __builtin_amdgcn_mfma_f32_16x16x32_bf16(af[i], bfr[j], acc[i][j], 0, 0, 0);
        __syncthreads();
    }

    if (col0 < 2048) {
#pragma unroll
        for (int i = 0; i < 4; ++i)
#pragma unroll
            for (int j = 0; j < 4; ++j)
#pragma unroll
                for (int r = 0; r < 4; ++r) {
                    int row = row0 + wr * 64 + i * 16 + quad * 4 + r;
                    int col = col0 + wc * 64 + j * 16 + l15;
                    Cqk[(size_t)row * 2048 + col] = f2bf(acc[i][j][r]);
                }
    } else {
#pragma unroll
        for (int i = 0; i < 4; ++i)
#pragma unroll
            for (int j = 0; j < 4; ++j) {
                int col = col0 + wc * 64 + j * 16 + l15 - 2048;   // h*64+d
                int row = row0 + wr * 64 + i * 16 + quad * 4;     // b*2048+n
                int bb = row >> 11, n = row & 2047;
                ushort4 o = {f2bf(acc[i][j][0]), f2bf(acc[i][j][1]),
                             f2bf(acc[i][j][2]), f2bf(acc[i][j][3])};
                *(ushort4*)&Vtg[((size_t)bb * INTER + col) * NN + n] = o;
            }
    }
}

// ---------------------------------------------------------------------------
// Tiled fp32 GEMM (out-projection): measured 131 TF = 83% of vector peak.
// ---------------------------------------------------------------------------
#define TILE 64
#define BK 16

__global__ __launch_bounds__(256) void gemm_fp32(const float* __restrict__ A,
                                                 const float* __restrict__ B,
                                                 float* __restrict__ C,
                                                 int M, int N, int K) {
    __shared__ float As[BK][TILE + 4];
    __shared__ float Bs[BK][TILE + 4];
    const int t  = threadIdx.x;
    const int tx = t & 15;
    const int ty = t >> 4;
    const int row0 = blockIdx.y * TILE;
    const int col0 = blockIdx.x * TILE;
    const int arow = t >> 2;
    const int akq  = (t & 3) * 4;
    const int brow = t >> 4;
    const int bcol = (t & 15) * 4;
    float acc[4][4] = {};
    for (int k0 = 0; k0 < K; k0 += BK) {
        float4 av = *(const float4*)&A[(size_t)(row0 + arow) * K + k0 + akq];
        float4 bv = *(const float4*)&B[(size_t)(k0 + brow) * N + col0 + bcol];
        As[akq + 0][arow] = av.x;
        As[akq + 1][arow] = av.y;
        As[akq + 2][arow] = av.z;
        As[akq + 3][arow] = av.w;
        *(float4*)&Bs[brow][bcol] = bv;
        __syncthreads();
#pragma unroll
        for (int kk = 0; kk < BK; ++kk) {
            float4 a4 = *(const float4*)&As[kk][ty * 4];
            float4 b4 = *(const float4*)&Bs[kk][tx * 4];
            float a[4] = {a4.x, a4.y, a4.z, a4.w};
            float b[4] = {b4.x, b4.y, b4.z, b4.w};
#pragma unroll
            for (int i = 0; i < 4; ++i)
#pragma unroll
                for (int j = 0; j < 4; ++j)
                    acc[i][j] += a[i] * b[j];
        }
        __syncthreads();
    }
#pragma unroll
    for (int i = 0; i < 4; ++i) {
        float4 o = {acc[i][0], acc[i][1], acc[i][2], acc[i][3]};
        *(float4*)&C[(size_t)(row0 + ty * 4 + i) * N + col0 + tx * 4] = o;
    }
}

// ---------------------------------------------------------------------------
// Segment-masked attention, MFMA bf16, single sweep, DOUBLE-BUFFERED staging.
// One barrier per j-tile: stage(t+1) issues right after the barrier and flies
// during compute(t). V staged from the pre-transposed global Vtg (b128).
// Semantics identical to rounds 2/3 (verified, absmax 9.8e-4).
// ---------------------------------------------------------------------------
__global__ __launch_bounds__(256, 2) void attn_seg_mfma(
        const unsigned short* __restrict__ qk,    // bf16 [4096][2048] = q|k
        const unsigned short* __restrict__ vtg,   // bf16 [2][1024][2048]
        const int* __restrict__ mask,             // [B,N,N]
        float* __restrict__ ctx) {                // [4096][1024]
    __shared__ __align__(16) unsigned short Ks[2][64][72];   // 18.4 KB
    __shared__ __align__(16) unsigned short Vt[2][64][72];   // 18.4 KB  [dim][key]
    __shared__ __align__(16) unsigned char  Mb[2][64][72];   //  9.2 KB
    __shared__ __align__(16) unsigned short El[4][16][72];   //  9.2 KB  per-wave E

    const int t    = threadIdx.x;
    const int w    = t >> 6;
    const int lane = t & 63;
    const int l15  = lane & 15;
    const int quad = lane >> 4;
    const int i0   = blockIdx.x * 64;
    const int h    = blockIdx.y;
    const int b    = blockIdx.z;

    bf16x8 qa0, qa1;
    {
        const unsigned short* qp =
            qk + (size_t)(b * NN + i0 + w * 16 + l15) * 2048 + h * HDIM + quad * 8;
        qa0 = *(const bf16x8*)qp;
        qa1 = *(const bf16x8*)(qp + 32);
    }

    bf16x8 onesb;
    {
        short ob = (l15 == 0) ? (short)0x3F80 : (short)0;
#pragma unroll
        for (int j = 0; j < 8; ++j) onesb[j] = ob;
    }

    f32x4 acc[NSEG][5];
#pragma unroll
    for (int m = 0; m < NSEG; ++m)
#pragma unroll
        for (int nt = 0; nt < 5; ++nt) acc[m][nt] = (f32x4){0.f, 0.f, 0.f, 0.f};

    auto stage = [&](int bb, int j0) {
#pragma unroll
        for (int it = 0; it < 2; ++it) {
            int id = t + it * 256, key = id >> 3, dc = (id & 7) * 8;
            *(bf16x8*)&Ks[bb][key][dc] =
                *(const bf16x8*)&qk[(size_t)(b * NN + j0 + key) * 2048 + 1024 + h * HDIM + dc];
        }
#pragma unroll
        for (int it = 0; it < 2; ++it) {
            int id = t + it * 256, d = id >> 3, c = (id & 7) * 8;
            *(bf16x8*)&Vt[bb][d][c] =
                *(const bf16x8*)&vtg[((size_t)b * INTER + h * HDIM + d) * NN + j0 + c];
        }
#pragma unroll
        for (int it = 0; it < 4; ++it) {
            int id = t + it * 256, row = id >> 4, c4 = (id & 15) * 4;
            int4 mv = *(const int4*)&mask[(size_t)(b * NN + i0 + row) * NN + j0 + c4];
            unsigned int p = (unsigned)(mv.x & 3) | ((unsigned)(mv.y & 3) << 8) |
                             ((unsigned)(mv.z & 3) << 16) | ((unsigned)(mv.w & 3) << 24);
            *(unsigned int*)&Mb[bb][row][c4] = p;
        }
    };

    stage(0, 0);

    for (int jt = 0; jt < NN / 64; ++jt) {
        __syncthreads();                        // buf[jt&1] ready; buf[nxt] free
        if (jt + 1 < NN / 64) stage((jt + 1) & 1, (jt + 1) * 64);
        const int bb = jt & 1;

        // ---- E = exp(scale * Q K^T) -> El (per-wave; same-wave DS ordering) ----
#pragma unroll
        for (int nt = 0; nt < 4; ++nt) {
            f32x4 s = {0.f, 0.f, 0.f, 0.f};
            bf16x8 kb0 = *(const bf16x8*)&Ks[bb][nt * 16 + l15][quad * 8];
            bf16x8 kb1 = *(const bf16x8*)&Ks[bb][nt * 16 + l15][32 + quad * 8];
            s = __builtin_amdgcn_mfma_f32_16x16x32_bf16(qa0, kb0, s, 0, 0, 0);
            s = __builtin_amdgcn_mfma_f32_16x16x32_bf16(qa1, kb1, s, 0, 0, 0);
#pragma unroll
            for (int r = 0; r < 4; ++r) {
                float e = __expf(s[r] * 0.03125f);      // scale = INTER^-0.5
                unsigned int u = __builtin_bit_cast(unsigned int, e);
                u += 0x7FFFu + ((u >> 16) & 1u);        // manual RNE to bf16
                El[w][quad * 4 + r][nt * 16 + l15] = (unsigned short)(u >> 16);
            }
        }

        // ---- PV: masked A variants x (4 dim tiles + ones tile) ----
#pragma unroll
        for (int ks = 0; ks < 2; ++ks) {
            union { int4 i; bf16x8 v; } ef;
            ef.i = *(const int4*)&El[w][l15][ks * 32 + quad * 8];
            uint2 sbv = *(const uint2*)&Mb[bb][w * 16 + l15][ks * 32 + quad * 8];
            unsigned int segb[8];
            segb[0] = sbv.x & 0xFF;  segb[1] = (sbv.x >> 8) & 0xFF;
            segb[2] = (sbv.x >> 16) & 0xFF; segb[3] = sbv.x >> 24;
            segb[4] = sbv.y & 0xFF;  segb[5] = (sbv.y >> 8) & 0xFF;
            segb[6] = (sbv.y >> 16) & 0xFF; segb[7] = sbv.y >> 24;
            unsigned int eL[4], eH[4];
#pragma unroll
            for (int d = 0; d < 4; ++d) {
                unsigned int e = ((const unsigned int*)&ef.i)[d];
                eL[d] = e & 0x0000FFFFu;
                eH[d] = e & 0xFFFF0000u;
            }
            bf16x8 vb[4];
#pragma unroll
            for (int nt = 0; nt < 4; ++nt)
                vb[nt] = *(const bf16x8*)&Vt[bb][nt * 16 + l15][ks * 32 + quad * 8];
#pragma unroll
            for (int m = 0; m < NSEG; ++m) {
                union { int4 i; bf16x8 v; } wm;
#pragma unroll
                for (int d = 0; d < 4; ++d) {
                    unsigned int lo = (segb[2 * d]     == (unsigned)m) ? eL[d] : 0u;
                    unsigned int hi = (segb[2 * d + 1] == (unsigned)m) ? eH[d] : 0u;
                    ((unsigned int*)&wm.i)[d] = lo | hi;
                }
#pragma unroll
                for (int nt = 0; nt < 4; ++nt)
                    acc[m][nt] = __builtin_amdgcn_mfma_f32_16x16x32_bf16(wm.v, vb[nt], acc[m][nt], 0, 0, 0);
                acc[m][4] = __builtin_amdgcn_mfma_f32_16x16x32_bf16(wm.v, onesb, acc[m][4], 0, 0, 0);
            }
        }
    }

    float rres[NSEG][4];
#pragma unroll
    for (int m = 0; m < NSEG; ++m)
#pragma unroll
        for (int r = 0; r < 4; ++r) {
            float sum = __shfl(acc[m][4][r], lane & 48, 64);
            rres[m][r] = (sum > 0.f) ? (1.f / sum) : 0.f;
        }
#pragma unroll
    for (int nt = 0; nt < 4; ++nt)
#pragma unroll
        for (int r = 0; r < 4; ++r) {
            float v = acc[0][nt][r] * rres[0][r] + acc[1][nt][r] * rres[1][r] +
                      acc[2][nt][r] * rres[2][r] + acc[3][nt][r] * rres[3][r];
            ctx[(size_t)(b * NN + i0 + w * 16 + quad * 4 + r) * INTER + h * HDIM + nt * 16 + l15] = v;
        }
}

// ---------------------------------------------------------------------------
extern "C" void kernel_launch(void* const* d_in, const int* in_sizes, int n_in,
                              void* d_out, int out_size, void* d_ws, size_t ws_size,
                              hipStream_t stream) {
    const float* features = (const float*)d_in[0];  // [B,N,DIM] fp32
    const int*   mask     = (const int*)d_in[1];    // [B,N,N]
    const float* W_qkv    = (const float*)d_in[2];  // [DIM, 3*INTER] fp32
    const float* W_out    = (const float*)d_in[3];  // [INTER, DIM] fp32
    float* out = (float*)d_out;                     // [B,N,DIM] fp32

    const int M = BB * NN;  // 4096
    char* ws = (char*)d_ws;
    unsigned short* qk2  = (unsigned short*)ws;                 // bf16 [4096][2048] 16.8 MB
    ws += (size_t)M * 2048 * 2;
    unsigned short* vtg  = (unsigned short*)ws;                 // bf16 [2][1024][2048] 8.4 MB
    ws += (size_t)BB * INTER * NN * 2;
    float* ctx = (float*)ws;                                    // fp32 [4096][1024] 16.8 MB
    ws += (size_t)M * INTER * 4;
    unsigned short* featb = (unsigned short*)ws;                // bf16 [4096][1024] 8.4 MB
    ws += (size_t)M * DIM * 2;
    unsigned short* wqt = (unsigned short*)ws;                  // bf16 [3072][1024] 6.3 MB

    dim3 blk(256);

    conv_f32_bf16<<<dim3((M * DIM) / 1024), blk, 0, stream>>>(features, featb);
    transp_f32_bf16<<<dim3(QKVW / 64, DIM / 64), blk, 0, stream>>>(W_qkv, wqt, DIM, QKVW);

    // 1) qkv projection: q|k -> qk2, v -> vtg (transposed per head)
    gemm_qkv_mfma<<<dim3(QKVW / 128, M / 128), blk, 0, stream>>>(featb, wqt, qk2, vtg);

    // 2) segment-masked attention -> ctx
    attn_seg_mfma<<<dim3(NN / 64, NHEAD, BB), blk, 0, stream>>>(qk2, vtg, mask, ctx);

    // 3) out = ctx @ W_out (fp32, exact)
    gemm_fp32<<<dim3(DIM / TILE, M / TILE), blk, 0, stream>>>(
        ctx, W_out, out, M, DIM, INTER);
}